// Round 6
// baseline (733.361 us; speedup 1.0000x reference)
//
#include <hip/hip_runtime.h>
#include <cstdint>
#include <cstddef>

// ---------------------------------------------------------------------------
// 4-layer GCN autoencoder, pull-based propagation.
// CSR built per launch with a 2-level counting sort (block-aggregated coarse
// scatter -> per-bucket LDS counting sort, u16 esrc).
// Propagation: out[d] = dinv[d]*sum_{s in N(d)u{d}} (dinv[s]*h[s]) (+b, relu);
// rows pre-scaled by dinv in the producer epilogue.
// k_pull: COLUMN-SLICED passes (16 floats = 64B per edge-gather per pass);
// each pass's gather footprint is N*64B = 3.2MB < 4MB per-XCD L2, so gathers
// become L2 hits instead of L3-random misses. Pass = blockIdx.y (x-fastest
// dispatch order keeps one pass co-resident; ordering affects speed only).
// Wave = 16 edge-groups x 4 lanes -> 16 edges per load instruction.
// ---------------------------------------------------------------------------

static inline int cdiv(int a, int b) { return (a + b - 1) / b; }

#define NBMAX 784   // >= cdiv(50000,64)=782 buckets
#define SCHUNK 8192 // edges per scatter block

// coarse histogram over dst>>6 with LDS aggregation
__global__ __launch_bounds__(256) void k_bhist(const int* __restrict__ dst,
                                               int* __restrict__ bh,
                                               int E, int nb, int perBlock) {
  __shared__ int h[NBMAX];
  for (int i = threadIdx.x; i < nb; i += 256) h[i] = 0;
  __syncthreads();
  int beg = blockIdx.x * perBlock;
  int end = min(beg + perBlock, E);
  for (int e = beg + threadIdx.x; e < end; e += 256)
    atomicAdd(&h[dst[e] >> 6], 1);
  __syncthreads();
  for (int i = threadIdx.x; i < nb; i += 256)
    if (h[i]) atomicAdd(&bh[i], h[i]);
}

// single-block exclusive scan of nb (<=1024) bucket sums -> boff, bcur
__global__ __launch_bounds__(256) void k_bscan(const int* __restrict__ bh,
                                               int* __restrict__ boff,
                                               int* __restrict__ bcur, int nb) {
  __shared__ int tsum[256];
  int t = threadIdx.x;
  int v[4];
  int s = 0;
#pragma unroll
  for (int i = 0; i < 4; ++i) {
    int idx = t * 4 + i;
    v[i] = (idx < nb) ? bh[idx] : 0;
    s += v[i];
  }
  tsum[t] = s;
  __syncthreads();
  int x = s;
  for (int d = 1; d < 256; d <<= 1) {
    int add = (t >= d) ? tsum[t - d] : 0;
    __syncthreads();
    x += add;
    tsum[t] = x;
    __syncthreads();
  }
  int base = x - s;  // exclusive prefix
#pragma unroll
  for (int i = 0; i < 4; ++i) {
    int idx = t * 4 + i;
    if (idx < nb) { boff[idx] = base; bcur[idx] = base; }
    base += v[i];
  }
  if (t == 255) boff[nb] = base;  // == E
}

// block-aggregated coarse scatter: one global atomic per (block,bucket)
__global__ __launch_bounds__(256) void k_bscatter(const int* __restrict__ src,
                                                  const int* __restrict__ dst,
                                                  int* __restrict__ bcur,
                                                  unsigned* __restrict__ tmp,
                                                  int E, int nb) {
  __shared__ int hist[NBMAX];
  __shared__ int base[NBMAX];
  int beg = blockIdx.x * SCHUNK;
  int end = min(beg + SCHUNK, E);
  for (int i = threadIdx.x; i < nb; i += 256) hist[i] = 0;
  __syncthreads();
  for (int e = beg + threadIdx.x; e < end; e += 256)
    atomicAdd(&hist[dst[e] >> 6], 1);
  __syncthreads();
  for (int b = threadIdx.x; b < nb; b += 256) {
    int c = hist[b];
    base[b] = c ? atomicAdd(&bcur[b], c) : 0;
    hist[b] = 0;  // reuse as local cursor
  }
  __syncthreads();
  for (int e = beg + threadIdx.x; e < end; e += 256) {
    int d = dst[e];
    int b = d >> 6;
    int lp = atomicAdd(&hist[b], 1);
    tmp[base[b] + lp] = ((unsigned)(d & 63) << 16) | (unsigned)src[e];
  }
}

// per-bucket counting sort (64 bins in LDS); emits u16 esrc, counts/offs/dinv
__global__ __launch_bounds__(256) void k_bsort(const unsigned* __restrict__ tmp,
                                               const int* __restrict__ boff,
                                               unsigned short* __restrict__ esrc,
                                               int* __restrict__ offs,
                                               int* __restrict__ counts,
                                               float* __restrict__ dinv,
                                               int N) {
  __shared__ int hist[64], cur[64];
  int b = blockIdx.x;
  int t = threadIdx.x;
  if (t < 64) hist[t] = 0;
  __syncthreads();
  int beg = boff[b], end = boff[b + 1];
  int cnt = end - beg;
  for (int i = t; i < cnt; i += 256) atomicAdd(&hist[tmp[beg + i] >> 16], 1);
  __syncthreads();
  if (t < 64) {
    int v = hist[t];
    int x = v;
#pragma unroll
    for (int d = 1; d < 64; d <<= 1) {
      int up = __shfl_up(x, d, 64);
      if (t >= d) x += up;
    }
    int ex = x - v;
    cur[t] = ex;
    int node = b * 64 + t;
    if (node < N) {
      counts[node] = v;
      offs[node] = beg + ex;
      dinv[node] = rsqrtf((float)(v + 1));
    }
  }
  __syncthreads();
  for (int i = t; i < cnt; i += 256) {
    unsigned v = tmp[beg + i];
    int pos = atomicAdd(&cur[v >> 16], 1);
    esrc[beg + pos] = (unsigned short)(v & 0xFFFFu);
  }
}

// Column-sliced pull. One wave per node per pass; pass = blockIdx.y covers
// columns [sl*16, sl*16+16). 16 edge-groups of 4 lanes: 16 edges per wave
// load instruction, 64B per edge per pass (L2-resident slice).
// Epilogue: t = dinv*acc (+bias) (relu) (*dinv).
template <int W, int BIAS, int RELU, int POST>
__global__ __launch_bounds__(256) void k_pull(const float* __restrict__ h,
                                              const unsigned short* __restrict__ esrc,
                                              const int* __restrict__ offs,
                                              const int* __restrict__ counts,
                                              const float* __restrict__ dinv,
                                              const float* __restrict__ bias,
                                              float* __restrict__ out, int n) {
  int node = blockIdx.x * 4 + (threadIdx.x >> 6);
  if (node >= n) return;
  int lane = threadIdx.x & 63;
  int g  = lane >> 2;          // edge group 0..15
  int fl = lane & 3;           // float4 slot within the 16-float slice
  int sl = blockIdx.y;         // column slice
  int cbase = sl * 16 + fl * 4;
  size_t rbase = (size_t)node * W + cbase;

  float4 acc = make_float4(0.f, 0.f, 0.f, 0.f);
  if (g == 0) acc = *(const float4*)&h[rbase];  // self loop

  int beg = offs[node];
  int cnt = counts[node];
  for (int j = g; j < cnt; j += 16) {
    int s = esrc[beg + j];
    float4 v = *(const float4*)&h[(size_t)s * W + cbase];
    acc.x += v.x; acc.y += v.y; acc.z += v.z; acc.w += v.w;
  }

  // reduce across the 16 edge-groups (xor strides 4..32)
#pragma unroll
  for (int d = 4; d < 64; d <<= 1) {
    acc.x += __shfl_xor(acc.x, d, 64);
    acc.y += __shfl_xor(acc.y, d, 64);
    acc.z += __shfl_xor(acc.z, d, 64);
    acc.w += __shfl_xor(acc.w, d, 64);
  }

  if (g == 0) {
    float dv = dinv[node];
    float4 t;
    t.x = dv * acc.x; t.y = dv * acc.y; t.z = dv * acc.z; t.w = dv * acc.w;
    if (BIAS) {
      float4 bv = *(const float4*)&bias[cbase];
      t.x += bv.x; t.y += bv.y; t.z += bv.z; t.w += bv.w;
    }
    if (RELU) {
      t.x = fmaxf(t.x, 0.f); t.y = fmaxf(t.y, 0.f);
      t.z = fmaxf(t.z, 0.f); t.w = fmaxf(t.w, 0.f);
    }
    if (POST) { t.x *= dv; t.y *= dv; t.z *= dv; t.w *= dv; }
    *(float4*)&out[rbase] = t;
  }
}

// C[N,M] = A[N,K] @ W[K,M] (+bias) (+relu) (*dinv[row]). 64x64 tile, 4x4/thr.
template <int BIAS, int RELU, int SCALE>
__global__ __launch_bounds__(256) void k_gemm(const float* __restrict__ A,
                                              const float* __restrict__ W,
                                              const float* __restrict__ bias,
                                              const float* __restrict__ dinv,
                                              float* __restrict__ C,
                                              int N, int K, int M) {
  __shared__ float As[64][68];  // [k][row]
  __shared__ float Bs[64][68];  // [k][col]
  const int tid = threadIdx.x;
  const int tx = tid & 15;
  const int ty = tid >> 4;
  const int row0 = blockIdx.x * 64;
  const int col0 = blockIdx.y * 64;

  float acc[4][4] = {};

  for (int kt = 0; kt < K; kt += 64) {
#pragma unroll
    for (int i = 0; i < 4; ++i) {
      int fid = tid + i * 256;
      int r = fid >> 4;
      int c4 = (fid & 15) << 2;
      float4 v = make_float4(0.f, 0.f, 0.f, 0.f);
      int gr = row0 + r;
      if (gr < N) v = *(const float4*)&A[(size_t)gr * K + kt + c4];
      As[c4 + 0][r] = v.x;
      As[c4 + 1][r] = v.y;
      As[c4 + 2][r] = v.z;
      As[c4 + 3][r] = v.w;
      float4 w = *(const float4*)&W[(size_t)(kt + r) * M + col0 + c4];
      *(float4*)&Bs[r][c4] = w;
    }
    __syncthreads();

#pragma unroll 8
    for (int k = 0; k < 64; ++k) {
      float4 a4 = *(const float4*)&As[k][ty << 2];
      float4 b4 = *(const float4*)&Bs[k][tx << 2];
      float ar[4] = {a4.x, a4.y, a4.z, a4.w};
      float br[4] = {b4.x, b4.y, b4.z, b4.w};
#pragma unroll
      for (int i = 0; i < 4; ++i)
#pragma unroll
        for (int j = 0; j < 4; ++j) acc[i][j] += ar[i] * br[j];
    }
    __syncthreads();
  }

  float4 bv = make_float4(0.f, 0.f, 0.f, 0.f);
  if (BIAS) bv = *(const float4*)&bias[col0 + (tx << 2)];
#pragma unroll
  for (int i = 0; i < 4; ++i) {
    int gr = row0 + (ty << 2) + i;
    if (gr >= N) continue;
    float4 o;
    o.x = acc[i][0] + bv.x;
    o.y = acc[i][1] + bv.y;
    o.z = acc[i][2] + bv.z;
    o.w = acc[i][3] + bv.w;
    if (RELU) {
      o.x = fmaxf(o.x, 0.f);
      o.y = fmaxf(o.y, 0.f);
      o.z = fmaxf(o.z, 0.f);
      o.w = fmaxf(o.w, 0.f);
    }
    if (SCALE) {
      float dv = dinv[gr];
      o.x *= dv; o.y *= dv; o.z *= dv; o.w *= dv;
    }
    *(float4*)&C[(size_t)gr * M + col0 + (tx << 2)] = o;
  }
}

extern "C" void kernel_launch(void* const* d_in, const int* in_sizes, int n_in,
                              void* d_out, int out_size, void* d_ws, size_t ws_size,
                              hipStream_t stream) {
  const float* x  = (const float*)d_in[0];
  const int*   ei = (const int*)d_in[1];
  const float* W1 = (const float*)d_in[2];
  const float* b1 = (const float*)d_in[3];
  const float* W2 = (const float*)d_in[4];
  const float* b2 = (const float*)d_in[5];
  const float* W3 = (const float*)d_in[6];
  const float* b3 = (const float*)d_in[7];
  const float* W4 = (const float*)d_in[8];
  const float* b4 = (const float*)d_in[9];

  const int N = in_sizes[0] / 256;  // 50000
  const int E = in_sizes[1] / 2;    // 1600000
  const int* src = ei;
  const int* dst = ei + E;
  const int nb = cdiv(N, 64);       // 782 buckets

  const int NP = 50176;  // padded N
  int*   bh     = (int*)d_ws;                      // NBMAX
  int*   boff   = bh + NBMAX;                      // NBMAX
  int*   bcur   = boff + NBMAX;                    // NBMAX
  int*   counts = bcur + NBMAX;                    // NP
  int*   offs   = counts + NP;                     // NP
  float* dinv   = (float*)(offs + NP);             // NP
  unsigned short* esrc = (unsigned short*)(dinv + NP);  // E u16
  float* A = (float*)(((uintptr_t)(esrc + E) + 255) & ~(uintptr_t)255);
  float* B = A + (size_t)N * 128;
  unsigned* tmp = (unsigned*)B;  // E u32 overlaid on B (dead before L1 pull)
  float* out = (float*)d_out;

  dim3 blk(256);

  // --- CSR build (2-level counting sort) + normalization ---
  hipMemsetAsync(bh, 0, NBMAX * sizeof(int), stream);
  {
    int nblk = 256;
    int perBlock = cdiv(E, nblk);
    k_bhist<<<nblk, blk, 0, stream>>>(dst, bh, E, nb, perBlock);
  }
  k_bscan<<<1, blk, 0, stream>>>(bh, boff, bcur, nb);
  k_bscatter<<<cdiv(E, SCHUNK), blk, 0, stream>>>(src, dst, bcur, tmp, E, nb);
  k_bsort<<<nb, blk, 0, stream>>>(tmp, boff, esrc, offs, counts, dinv, N);

  const int nodeBlocks = cdiv(N, 4);  // 12500
  dim3 gp128(nodeBlocks, 128 / 16);   // 8 passes
  dim3 gp64(nodeBlocks, 64 / 16);     // 4 passes

  // L1: t1' = dinv o (x @ W1); h1 = relu(dinv*acc + b1)          [A -> B]
  {
    dim3 g(cdiv(N, 64), 128 / 64);
    k_gemm<0, 0, 1><<<g, blk, 0, stream>>>(x, W1, nullptr, dinv, A, N, 256, 128);
    k_pull<128, 1, 1, 0><<<gp128, blk, 0, stream>>>(A, esrc, offs, counts, dinv, b1, B, N);
  }
  // L2: t2' = dinv o (h1 @ W2); z' = dinv*relu(dinv*acc + b2)    [B -> A -> B]
  {
    dim3 g(cdiv(N, 64), 64 / 64);
    k_gemm<0, 0, 1><<<g, blk, 0, stream>>>(B, W2, nullptr, dinv, A, N, 128, 64);
    k_pull<64, 1, 1, 1><<<gp64, blk, 0, stream>>>(A, esrc, offs, counts, dinv, b2, B, N);
  }
  // L3: p3 = dinv*acc(z'); h3' = dinv o relu(p3 @ W3 + b3)       [B -> A -> B]
  {
    k_pull<64, 0, 0, 0><<<gp64, blk, 0, stream>>>(B, esrc, offs, counts, dinv, nullptr, A, N);
    dim3 g(cdiv(N, 64), 128 / 64);
    k_gemm<1, 1, 1><<<g, blk, 0, stream>>>(A, W3, b3, dinv, B, N, 64, 128);
  }
  // L4: p4 = dinv*acc(h3'); out = p4 @ W4 + b4                   [B -> A -> out]
  {
    k_pull<128, 0, 0, 0><<<gp128, blk, 0, stream>>>(B, esrc, offs, counts, dinv, nullptr, A, N);
    dim3 g(cdiv(N, 64), 256 / 64);
    k_gemm<1, 0, 0><<<g, blk, 0, stream>>>(A, W4, b4, nullptr, out, N, 128, 256);
  }
}

// Round 8
// 565.147 us; speedup vs baseline: 1.2976x; 1.2976x over previous
//
#include <hip/hip_runtime.h>
#include <cstdint>
#include <cstddef>

// ---------------------------------------------------------------------------
// 4-layer GCN autoencoder, pull-based propagation.
// CSR built per launch with a 2-level counting sort (block-aggregated coarse
// scatter -> per-bucket LDS counting sort, u16 esrc).
// Propagation: out[d] = dinv[d]*sum_{s in N(d)u{d}} (dinv[s]*h[s]) (+b, relu);
// rows pre-scaled by dinv in the producer epilogue.
// k_pull (R4 structure): float4 gathers, lane-group edge parallelism
// (2 edges/instr at w128, 4 at w64), 4x unroll, shfl_xor group reduce.
// NT stores on pull outputs that are only streamed by the next consumer.
// GEMM: 128x128 tile (BK=32, 8x8/thread) for M>=128; 64x64 for M=64.
// ---------------------------------------------------------------------------

static inline int cdiv(int a, int b) { return (a + b - 1) / b; }

typedef float nfloat4 __attribute__((ext_vector_type(4)));  // NT-store-able

__device__ inline void nt_store4(float* p, float a, float b, float c, float d) {
  nfloat4 v = {a, b, c, d};
  __builtin_nontemporal_store(v, (nfloat4*)p);
}

#define NBMAX 784   // >= cdiv(50000,64)=782 buckets
#define SCHUNK 8192 // edges per scatter block

// coarse histogram over dst>>6 with LDS aggregation
__global__ __launch_bounds__(256) void k_bhist(const int* __restrict__ dst,
                                               int* __restrict__ bh,
                                               int E, int nb, int perBlock) {
  __shared__ int h[NBMAX];
  for (int i = threadIdx.x; i < nb; i += 256) h[i] = 0;
  __syncthreads();
  int beg = blockIdx.x * perBlock;
  int end = min(beg + perBlock, E);
  for (int e = beg + threadIdx.x; e < end; e += 256)
    atomicAdd(&h[dst[e] >> 6], 1);
  __syncthreads();
  for (int i = threadIdx.x; i < nb; i += 256)
    if (h[i]) atomicAdd(&bh[i], h[i]);
}

// single-block exclusive scan of nb (<=1024) bucket sums -> boff, bcur
__global__ __launch_bounds__(256) void k_bscan(const int* __restrict__ bh,
                                               int* __restrict__ boff,
                                               int* __restrict__ bcur, int nb) {
  __shared__ int tsum[256];
  int t = threadIdx.x;
  int v[4];
  int s = 0;
#pragma unroll
  for (int i = 0; i < 4; ++i) {
    int idx = t * 4 + i;
    v[i] = (idx < nb) ? bh[idx] : 0;
    s += v[i];
  }
  tsum[t] = s;
  __syncthreads();
  int x = s;
  for (int d = 1; d < 256; d <<= 1) {
    int add = (t >= d) ? tsum[t - d] : 0;
    __syncthreads();
    x += add;
    tsum[t] = x;
    __syncthreads();
  }
  int base = x - s;  // exclusive prefix
#pragma unroll
  for (int i = 0; i < 4; ++i) {
    int idx = t * 4 + i;
    if (idx < nb) { boff[idx] = base; bcur[idx] = base; }
    base += v[i];
  }
  if (t == 255) boff[nb] = base;  // == E
}

// block-aggregated coarse scatter: one global atomic per (block,bucket)
__global__ __launch_bounds__(256) void k_bscatter(const int* __restrict__ src,
                                                  const int* __restrict__ dst,
                                                  int* __restrict__ bcur,
                                                  unsigned* __restrict__ tmp,
                                                  int E, int nb) {
  __shared__ int hist[NBMAX];
  __shared__ int base[NBMAX];
  int beg = blockIdx.x * SCHUNK;
  int end = min(beg + SCHUNK, E);
  for (int i = threadIdx.x; i < nb; i += 256) hist[i] = 0;
  __syncthreads();
  for (int e = beg + threadIdx.x; e < end; e += 256)
    atomicAdd(&hist[dst[e] >> 6], 1);
  __syncthreads();
  for (int b = threadIdx.x; b < nb; b += 256) {
    int c = hist[b];
    base[b] = c ? atomicAdd(&bcur[b], c) : 0;
    hist[b] = 0;  // reuse as local cursor
  }
  __syncthreads();
  for (int e = beg + threadIdx.x; e < end; e += 256) {
    int d = dst[e];
    int b = d >> 6;
    int lp = atomicAdd(&hist[b], 1);
    tmp[base[b] + lp] = ((unsigned)(d & 63) << 16) | (unsigned)src[e];
  }
}

// per-bucket counting sort (64 bins in LDS); emits u16 esrc, counts/offs/dinv
__global__ __launch_bounds__(256) void k_bsort(const unsigned* __restrict__ tmp,
                                               const int* __restrict__ boff,
                                               unsigned short* __restrict__ esrc,
                                               int* __restrict__ offs,
                                               int* __restrict__ counts,
                                               float* __restrict__ dinv,
                                               int N) {
  __shared__ int hist[64], cur[64];
  int b = blockIdx.x;
  int t = threadIdx.x;
  if (t < 64) hist[t] = 0;
  __syncthreads();
  int beg = boff[b], end = boff[b + 1];
  int cnt = end - beg;
  for (int i = t; i < cnt; i += 256) atomicAdd(&hist[tmp[beg + i] >> 16], 1);
  __syncthreads();
  if (t < 64) {
    int v = hist[t];
    int x = v;
#pragma unroll
    for (int d = 1; d < 64; d <<= 1) {
      int up = __shfl_up(x, d, 64);
      if (t >= d) x += up;
    }
    int ex = x - v;
    cur[t] = ex;
    int node = b * 64 + t;
    if (node < N) {
      counts[node] = v;
      offs[node] = beg + ex;
      dinv[node] = rsqrtf((float)(v + 1));
    }
  }
  __syncthreads();
  for (int i = t; i < cnt; i += 256) {
    unsigned v = tmp[beg + i];
    int pos = atomicAdd(&cur[v >> 16], 1);
    esrc[beg + pos] = (unsigned short)(v & 0xFFFFu);
  }
}

// Pull propagation: 1 wave per node, float4 gathers (R4 structure).
// WIDE=1: width 128, 2 lane-groups of 32 (2 edges per load instruction).
// WIDE=0: width 64,  4 lane-groups of 16 (4 edges per load instruction).
// Epilogue: t = dinv*acc (+bias) (relu) (*dinv); group-reduce via shfl_xor.
// NT=1: non-temporal store (output only streamed by next consumer).
template <int WIDE, int BIAS, int RELU, int POST, int NT>
__global__ __launch_bounds__(256) void k_pull(const float* __restrict__ h,
                                              const unsigned short* __restrict__ esrc,
                                              const int* __restrict__ offs,
                                              const int* __restrict__ counts,
                                              const float* __restrict__ dinv,
                                              const float* __restrict__ bias,
                                              float* __restrict__ out, int n) {
  const int W   = WIDE ? 128 : 64;  // floats per row
  const int LPR = W / 4;            // lanes per row: 32 / 16
  const int GRP = 64 / LPR;         // edge groups:    2 / 4
  int node = blockIdx.x * 4 + (threadIdx.x >> 6);
  if (node >= n) return;
  int lane = threadIdx.x & 63;
  int g  = lane / LPR;   // which edge slot this lane serves
  int fl = lane % LPR;   // feature quad index
  size_t rbase = (size_t)node * W;

  float4 acc = make_float4(0.f, 0.f, 0.f, 0.f);
  if (g == 0) acc = *(const float4*)&h[rbase + fl * 4];  // self loop

  int beg = offs[node];
  int cnt = counts[node];
  int j = g;
  for (; j + 3 * GRP < cnt; j += 4 * GRP) {
    int s0 = esrc[beg + j];
    int s1 = esrc[beg + j + GRP];
    int s2 = esrc[beg + j + 2 * GRP];
    int s3 = esrc[beg + j + 3 * GRP];
    float4 v0 = *(const float4*)&h[(size_t)s0 * W + fl * 4];
    float4 v1 = *(const float4*)&h[(size_t)s1 * W + fl * 4];
    float4 v2 = *(const float4*)&h[(size_t)s2 * W + fl * 4];
    float4 v3 = *(const float4*)&h[(size_t)s3 * W + fl * 4];
    acc.x += (v0.x + v1.x) + (v2.x + v3.x);
    acc.y += (v0.y + v1.y) + (v2.y + v3.y);
    acc.z += (v0.z + v1.z) + (v2.z + v3.z);
    acc.w += (v0.w + v1.w) + (v2.w + v3.w);
  }
  for (; j < cnt; j += GRP) {
    int s = esrc[beg + j];
    float4 v = *(const float4*)&h[(size_t)s * W + fl * 4];
    acc.x += v.x; acc.y += v.y; acc.z += v.z; acc.w += v.w;
  }

  // reduce partial sums across the GRP lane-groups (same fl, different g)
#pragma unroll
  for (int d = LPR; d < 64; d <<= 1) {
    acc.x += __shfl_xor(acc.x, d, 64);
    acc.y += __shfl_xor(acc.y, d, 64);
    acc.z += __shfl_xor(acc.z, d, 64);
    acc.w += __shfl_xor(acc.w, d, 64);
  }

  if (g == 0) {
    float dv = dinv[node];
    float tx = dv * acc.x, ty = dv * acc.y, tz = dv * acc.z, tw = dv * acc.w;
    if (BIAS) {
      float4 bv = *(const float4*)&bias[fl * 4];
      tx += bv.x; ty += bv.y; tz += bv.z; tw += bv.w;
    }
    if (RELU) {
      tx = fmaxf(tx, 0.f); ty = fmaxf(ty, 0.f);
      tz = fmaxf(tz, 0.f); tw = fmaxf(tw, 0.f);
    }
    if (POST) { tx *= dv; ty *= dv; tz *= dv; tw *= dv; }
    if (NT) {
      nt_store4(&out[rbase + fl * 4], tx, ty, tz, tw);
    } else {
      *(float4*)&out[rbase + fl * 4] = make_float4(tx, ty, tz, tw);
    }
  }
}

// C[N,M] = A[N,K] @ W[K,M] (+bias) (+relu) (*dinv[row]). 64x64 tile, 4x4/thr.
template <int BIAS, int RELU, int SCALE>
__global__ __launch_bounds__(256) void k_gemm(const float* __restrict__ A,
                                              const float* __restrict__ W,
                                              const float* __restrict__ bias,
                                              const float* __restrict__ dinv,
                                              float* __restrict__ C,
                                              int N, int K, int M) {
  __shared__ float As[64][68];  // [k][row]
  __shared__ float Bs[64][68];  // [k][col]
  const int tid = threadIdx.x;
  const int tx = tid & 15;
  const int ty = tid >> 4;
  const int row0 = blockIdx.x * 64;
  const int col0 = blockIdx.y * 64;

  float acc[4][4] = {};

  for (int kt = 0; kt < K; kt += 64) {
#pragma unroll
    for (int i = 0; i < 4; ++i) {
      int fid = tid + i * 256;
      int r = fid >> 4;
      int c4 = (fid & 15) << 2;
      float4 v = make_float4(0.f, 0.f, 0.f, 0.f);
      int gr = row0 + r;
      if (gr < N) v = *(const float4*)&A[(size_t)gr * K + kt + c4];
      As[c4 + 0][r] = v.x;
      As[c4 + 1][r] = v.y;
      As[c4 + 2][r] = v.z;
      As[c4 + 3][r] = v.w;
      float4 w = *(const float4*)&W[(size_t)(kt + r) * M + col0 + c4];
      *(float4*)&Bs[r][c4] = w;
    }
    __syncthreads();

#pragma unroll 8
    for (int k = 0; k < 64; ++k) {
      float4 a4 = *(const float4*)&As[k][ty << 2];
      float4 b4 = *(const float4*)&Bs[k][tx << 2];
      float ar[4] = {a4.x, a4.y, a4.z, a4.w};
      float br[4] = {b4.x, b4.y, b4.z, b4.w};
#pragma unroll
      for (int i = 0; i < 4; ++i)
#pragma unroll
        for (int j = 0; j < 4; ++j) acc[i][j] += ar[i] * br[j];
    }
    __syncthreads();
  }

  float4 bv = make_float4(0.f, 0.f, 0.f, 0.f);
  if (BIAS) bv = *(const float4*)&bias[col0 + (tx << 2)];
#pragma unroll
  for (int i = 0; i < 4; ++i) {
    int gr = row0 + (ty << 2) + i;
    if (gr >= N) continue;
    float4 o;
    o.x = acc[i][0] + bv.x;
    o.y = acc[i][1] + bv.y;
    o.z = acc[i][2] + bv.z;
    o.w = acc[i][3] + bv.w;
    if (RELU) {
      o.x = fmaxf(o.x, 0.f);
      o.y = fmaxf(o.y, 0.f);
      o.z = fmaxf(o.z, 0.f);
      o.w = fmaxf(o.w, 0.f);
    }
    if (SCALE) {
      float dv = dinv[gr];
      o.x *= dv; o.y *= dv; o.z *= dv; o.w *= dv;
    }
    *(float4*)&C[(size_t)gr * M + col0 + (tx << 2)] = o;
  }
}

// C[N,M] = A[N,K] @ W[K,M] (+bias) (+relu) (*dinv) (NT). 128x128 tile,
// BK=32, 8x8 per thread. Requires K%32==0, M%128==0 per blockIdx.y tile.
template <int BIAS, int RELU, int SCALE, int NT>
__global__ __launch_bounds__(256) void k_gemm128(const float* __restrict__ A,
                                                 const float* __restrict__ W,
                                                 const float* __restrict__ bias,
                                                 const float* __restrict__ dinv,
                                                 float* __restrict__ C,
                                                 int N, int K, int M) {
  __shared__ float As[32][133];  // [k][row], transposed A tile
  __shared__ float Bs[32][133];  // [k][col]
  const int tid = threadIdx.x;
  const int tx = tid & 15;       // col micro-tile (8 cols)
  const int ty = tid >> 4;       // row micro-tile (8 rows)
  const int row0 = blockIdx.x * 128;
  const int col0 = blockIdx.y * 128;

  float acc[8][8] = {};

  for (int kt = 0; kt < K; kt += 32) {
    // stage A: 128 rows x 32 k (transpose into As[k][row])
#pragma unroll
    for (int i = 0; i < 4; ++i) {
      int fid = tid + i * 256;       // 0..1023
      int r  = fid >> 3;             // 0..127
      int c4 = (fid & 7) << 2;       // 0..28
      float4 v = make_float4(0.f, 0.f, 0.f, 0.f);
      int gr = row0 + r;
      if (gr < N) v = *(const float4*)&A[(size_t)gr * K + kt + c4];
      As[c4 + 0][r] = v.x;
      As[c4 + 1][r] = v.y;
      As[c4 + 2][r] = v.z;
      As[c4 + 3][r] = v.w;
    }
    // stage B: 32 k-rows x 128 cols
#pragma unroll
    for (int i = 0; i < 4; ++i) {
      int fid = tid + i * 256;       // 0..1023
      int r  = fid >> 5;             // 0..31
      int c4 = (fid & 31) << 2;      // 0..124
      float4 w = *(const float4*)&W[(size_t)(kt + r) * M + col0 + c4];
      *(float4*)&Bs[r][c4] = w;
    }
    __syncthreads();

#pragma unroll 4
    for (int k = 0; k < 32; ++k) {
      float4 a0 = *(const float4*)&As[k][ty * 8];
      float4 a1 = *(const float4*)&As[k][ty * 8 + 4];
      float4 b0 = *(const float4*)&Bs[k][tx * 8];
      float4 b1 = *(const float4*)&Bs[k][tx * 8 + 4];
      float ar[8] = {a0.x, a0.y, a0.z, a0.w, a1.x, a1.y, a1.z, a1.w};
      float br[8] = {b0.x, b0.y, b0.z, b0.w, b1.x, b1.y, b1.z, b1.w};
#pragma unroll
      for (int i = 0; i < 8; ++i)
#pragma unroll
        for (int j = 0; j < 8; ++j) acc[i][j] += ar[i] * br[j];
    }
    __syncthreads();
  }

  float4 bv0 = make_float4(0.f, 0.f, 0.f, 0.f), bv1 = bv0;
  if (BIAS) {
    bv0 = *(const float4*)&bias[col0 + tx * 8];
    bv1 = *(const float4*)&bias[col0 + tx * 8 + 4];
  }
#pragma unroll
  for (int i = 0; i < 8; ++i) {
    int gr = row0 + ty * 8 + i;
    if (gr >= N) continue;
    float dv = SCALE ? dinv[gr] : 1.0f;
    float o[8];
#pragma unroll
    for (int j = 0; j < 8; ++j) {
      float bj = (j < 4) ? (&bv0.x)[j] : (&bv1.x)[j - 4];
      float v = acc[i][j] + bj;
      if (RELU) v = fmaxf(v, 0.f);
      if (SCALE) v *= dv;
      o[j] = v;
    }
    float* p = &C[(size_t)gr * M + col0 + tx * 8];
    if (NT) {
      nt_store4(p, o[0], o[1], o[2], o[3]);
      nt_store4(p + 4, o[4], o[5], o[6], o[7]);
    } else {
      *(float4*)p = make_float4(o[0], o[1], o[2], o[3]);
      *(float4*)(p + 4) = make_float4(o[4], o[5], o[6], o[7]);
    }
  }
}

extern "C" void kernel_launch(void* const* d_in, const int* in_sizes, int n_in,
                              void* d_out, int out_size, void* d_ws, size_t ws_size,
                              hipStream_t stream) {
  const float* x  = (const float*)d_in[0];
  const int*   ei = (const int*)d_in[1];
  const float* W1 = (const float*)d_in[2];
  const float* b1 = (const float*)d_in[3];
  const float* W2 = (const float*)d_in[4];
  const float* b2 = (const float*)d_in[5];
  const float* W3 = (const float*)d_in[6];
  const float* b3 = (const float*)d_in[7];
  const float* W4 = (const float*)d_in[8];
  const float* b4 = (const float*)d_in[9];

  const int N = in_sizes[0] / 256;  // 50000
  const int E = in_sizes[1] / 2;    // 1600000
  const int* src = ei;
  const int* dst = ei + E;
  const int nb = cdiv(N, 64);       // 782 buckets

  const int NP = 50176;  // padded N
  int*   bh     = (int*)d_ws;                      // NBMAX
  int*   boff   = bh + NBMAX;                      // NBMAX
  int*   bcur   = boff + NBMAX;                    // NBMAX
  int*   counts = bcur + NBMAX;                    // NP
  int*   offs   = counts + NP;                     // NP
  float* dinv   = (float*)(offs + NP);             // NP
  unsigned short* esrc = (unsigned short*)(dinv + NP);  // E u16
  float* A = (float*)(((uintptr_t)(esrc + E) + 255) & ~(uintptr_t)255);
  float* B = A + (size_t)N * 128;
  unsigned* tmp = (unsigned*)B;  // E u32 overlaid on B (dead before L1 pull)
  float* out = (float*)d_out;

  dim3 blk(256);

  // --- CSR build (2-level counting sort) + normalization ---
  (void)hipMemsetAsync(bh, 0, NBMAX * sizeof(int), stream);
  {
    int nblk = 256;
    int perBlock = cdiv(E, nblk);
    k_bhist<<<nblk, blk, 0, stream>>>(dst, bh, E, nb, perBlock);
  }
  k_bscan<<<1, blk, 0, stream>>>(bh, boff, bcur, nb);
  k_bscatter<<<cdiv(E, SCHUNK), blk, 0, stream>>>(src, dst, bcur, tmp, E, nb);
  k_bsort<<<nb, blk, 0, stream>>>(tmp, boff, esrc, offs, counts, dinv, N);

  dim3 gpull(cdiv(N, 4));

  // L1: t1' = dinv o (x @ W1); h1 = relu(dinv*acc + b1)          [A -> B]
  {
    dim3 g(cdiv(N, 128), 128 / 128);
    k_gemm128<0, 0, 1, 0><<<g, blk, 0, stream>>>(x, W1, nullptr, dinv, A, N, 256, 128);
    k_pull<1, 1, 1, 0, 1><<<gpull, blk, 0, stream>>>(A, esrc, offs, counts, dinv, b1, B, N);
  }
  // L2: t2' = dinv o (h1 @ W2); z' = dinv*relu(dinv*acc + b2)    [B -> A -> B]
  {
    dim3 g(cdiv(N, 64), 64 / 64);
    k_gemm<0, 0, 1><<<g, blk, 0, stream>>>(B, W2, nullptr, dinv, A, N, 128, 64);
    k_pull<0, 1, 1, 1, 0><<<gpull, blk, 0, stream>>>(A, esrc, offs, counts, dinv, b2, B, N);
  }
  // L3: p3 = dinv*acc(z'); h3' = dinv o relu(p3 @ W3 + b3)       [B -> A -> B]
  {
    k_pull<0, 0, 0, 0, 1><<<gpull, blk, 0, stream>>>(B, esrc, offs, counts, dinv, nullptr, A, N);
    dim3 g(cdiv(N, 128), 128 / 128);
    k_gemm128<1, 1, 1, 0><<<g, blk, 0, stream>>>(A, W3, b3, dinv, B, N, 64, 128);
  }
  // L4: p4 = dinv*acc(h3'); out = p4 @ W4 + b4                   [B -> A -> out]
  {
    k_pull<1, 0, 0, 0, 1><<<gpull, blk, 0, stream>>>(B, esrc, offs, counts, dinv, nullptr, A, N);
    dim3 g(cdiv(N, 128), 256 / 128);
    k_gemm128<1, 0, 0, 1><<<g, blk, 0, stream>>>(A, W4, b4, nullptr, out, N, 128, 256);
  }
}

// Round 9
// 374.253 us; speedup vs baseline: 1.9595x; 1.5101x over previous
//
#include <hip/hip_runtime.h>
#include <cstdint>
#include <cstddef>

// ---------------------------------------------------------------------------
// 4-layer GCN autoencoder, pull-based propagation.
// CSR built per launch with a 2-level counting sort (block-aggregated coarse
// scatter -> per-bucket LDS counting sort, u16 esrc).
// Propagation: out[d] = dinv[d]*sum_{s in N(d)u{d}} (dinv[s]*h[s]) (+b, relu);
// rows pre-scaled by dinv in the producer epilogue.
// KEY (R8): every GATHERED operand is stored fp16 (_Float16) -> gather bytes
// halve (pull is L2-miss-byte-bound at ~3.4 TB/s), L2 hit rate doubles.
// Accumulation stays fp32; streamed intermediates and d_out stay fp32.
// Pull: 16B half8 lanes; 4 edge-groups (w128) / 8 (w64) per wave instr.
// GEMM: proven 64x64 tile, 4x4/thread; fp16- or fp32-output epilogue.
// ---------------------------------------------------------------------------

static inline int cdiv(int a, int b) { return (a + b - 1) / b; }

typedef _Float16 half8v __attribute__((ext_vector_type(8)));
typedef _Float16 half4v __attribute__((ext_vector_type(4)));

#define NBMAX 784   // >= cdiv(50000,64)=782 buckets
#define SCHUNK 8192 // edges per scatter block

// coarse histogram over dst>>6 with LDS aggregation
__global__ __launch_bounds__(256) void k_bhist(const int* __restrict__ dst,
                                               int* __restrict__ bh,
                                               int E, int nb, int perBlock) {
  __shared__ int h[NBMAX];
  for (int i = threadIdx.x; i < nb; i += 256) h[i] = 0;
  __syncthreads();
  int beg = blockIdx.x * perBlock;
  int end = min(beg + perBlock, E);
  for (int e = beg + threadIdx.x; e < end; e += 256)
    atomicAdd(&h[dst[e] >> 6], 1);
  __syncthreads();
  for (int i = threadIdx.x; i < nb; i += 256)
    if (h[i]) atomicAdd(&bh[i], h[i]);
}

// single-block exclusive scan of nb (<=1024) bucket sums -> boff, bcur
__global__ __launch_bounds__(256) void k_bscan(const int* __restrict__ bh,
                                               int* __restrict__ boff,
                                               int* __restrict__ bcur, int nb) {
  __shared__ int tsum[256];
  int t = threadIdx.x;
  int v[4];
  int s = 0;
#pragma unroll
  for (int i = 0; i < 4; ++i) {
    int idx = t * 4 + i;
    v[i] = (idx < nb) ? bh[idx] : 0;
    s += v[i];
  }
  tsum[t] = s;
  __syncthreads();
  int x = s;
  for (int d = 1; d < 256; d <<= 1) {
    int add = (t >= d) ? tsum[t - d] : 0;
    __syncthreads();
    x += add;
    tsum[t] = x;
    __syncthreads();
  }
  int base = x - s;  // exclusive prefix
#pragma unroll
  for (int i = 0; i < 4; ++i) {
    int idx = t * 4 + i;
    if (idx < nb) { boff[idx] = base; bcur[idx] = base; }
    base += v[i];
  }
  if (t == 255) boff[nb] = base;  // == E
}

// block-aggregated coarse scatter: one global atomic per (block,bucket)
__global__ __launch_bounds__(256) void k_bscatter(const int* __restrict__ src,
                                                  const int* __restrict__ dst,
                                                  int* __restrict__ bcur,
                                                  unsigned* __restrict__ tmp,
                                                  int E, int nb) {
  __shared__ int hist[NBMAX];
  __shared__ int base[NBMAX];
  int beg = blockIdx.x * SCHUNK;
  int end = min(beg + SCHUNK, E);
  for (int i = threadIdx.x; i < nb; i += 256) hist[i] = 0;
  __syncthreads();
  for (int e = beg + threadIdx.x; e < end; e += 256)
    atomicAdd(&hist[dst[e] >> 6], 1);
  __syncthreads();
  for (int b = threadIdx.x; b < nb; b += 256) {
    int c = hist[b];
    base[b] = c ? atomicAdd(&bcur[b], c) : 0;
    hist[b] = 0;  // reuse as local cursor
  }
  __syncthreads();
  for (int e = beg + threadIdx.x; e < end; e += 256) {
    int d = dst[e];
    int b = d >> 6;
    int lp = atomicAdd(&hist[b], 1);
    tmp[base[b] + lp] = ((unsigned)(d & 63) << 16) | (unsigned)src[e];
  }
}

// per-bucket counting sort (64 bins in LDS); emits u16 esrc, counts/offs/dinv
__global__ __launch_bounds__(256) void k_bsort(const unsigned* __restrict__ tmp,
                                               const int* __restrict__ boff,
                                               unsigned short* __restrict__ esrc,
                                               int* __restrict__ offs,
                                               int* __restrict__ counts,
                                               float* __restrict__ dinv,
                                               int N) {
  __shared__ int hist[64], cur[64];
  int b = blockIdx.x;
  int t = threadIdx.x;
  if (t < 64) hist[t] = 0;
  __syncthreads();
  int beg = boff[b], end = boff[b + 1];
  int cnt = end - beg;
  for (int i = t; i < cnt; i += 256) atomicAdd(&hist[tmp[beg + i] >> 16], 1);
  __syncthreads();
  if (t < 64) {
    int v = hist[t];
    int x = v;
#pragma unroll
    for (int d = 1; d < 64; d <<= 1) {
      int up = __shfl_up(x, d, 64);
      if (t >= d) x += up;
    }
    int ex = x - v;
    cur[t] = ex;
    int node = b * 64 + t;
    if (node < N) {
      counts[node] = v;
      offs[node] = beg + ex;
      dinv[node] = rsqrtf((float)(v + 1));
    }
  }
  __syncthreads();
  for (int i = t; i < cnt; i += 256) {
    unsigned v = tmp[beg + i];
    int pos = atomicAdd(&cur[v >> 16], 1);
    esrc[beg + pos] = (unsigned short)(v & 0xFFFFu);
  }
}

// fp16-gather pull. W = halves per row (128 or 64). One wave per node.
// LPR = W/8 lanes cover a row with 16B half8 loads; GRP = 64/LPR edges per
// wave load instruction (4 at w128, 8 at w64), 2x unrolled.
// Epilogue (group 0): t = dinv*acc (+bias) (relu) (*dinv); out fp16 or fp32.
template <int W, int BIAS, int RELU, int POST, int OUTF16>
__global__ __launch_bounds__(256) void k_pull16(const _Float16* __restrict__ h,
                                                const unsigned short* __restrict__ esrc,
                                                const int* __restrict__ offs,
                                                const int* __restrict__ counts,
                                                const float* __restrict__ dinv,
                                                const float* __restrict__ bias,
                                                void* __restrict__ outv, int n) {
  const int LPR = W / 8;    // lanes per row: 16 (w128) / 8 (w64)
  const int GRP = 64 / LPR; // edge groups:    4        / 8
  int node = blockIdx.x * 4 + (threadIdx.x >> 6);
  if (node >= n) return;
  int lane = threadIdx.x & 63;
  int g  = lane / LPR;
  int fl = lane % LPR;
  size_t rbase = (size_t)node * W + fl * 8;

  float acc[8] = {};
  if (g == 0) {
    half8v sv = *(const half8v*)&h[rbase];  // self loop
#pragma unroll
    for (int q = 0; q < 8; ++q) acc[q] = (float)sv[q];
  }

  int beg = offs[node];
  int cnt = counts[node];
  int j = g;
  for (; j + GRP < cnt; j += 2 * GRP) {
    int s0 = esrc[beg + j];
    int s1 = esrc[beg + j + GRP];
    half8v v0 = *(const half8v*)&h[(size_t)s0 * W + fl * 8];
    half8v v1 = *(const half8v*)&h[(size_t)s1 * W + fl * 8];
#pragma unroll
    for (int q = 0; q < 8; ++q) acc[q] += (float)v0[q] + (float)v1[q];
  }
  if (j < cnt) {
    int s = esrc[beg + j];
    half8v v = *(const half8v*)&h[(size_t)s * W + fl * 8];
#pragma unroll
    for (int q = 0; q < 8; ++q) acc[q] += (float)v[q];
  }

  // reduce partial sums across edge-groups (same fl, different g)
#pragma unroll
  for (int d = LPR; d < 64; d <<= 1) {
#pragma unroll
    for (int q = 0; q < 8; ++q) acc[q] += __shfl_xor(acc[q], d, 64);
  }

  if (g == 0) {
    float dv = dinv[node];
    float t[8];
#pragma unroll
    for (int q = 0; q < 8; ++q) t[q] = dv * acc[q];
    if (BIAS) {
#pragma unroll
      for (int q = 0; q < 8; ++q) t[q] += bias[fl * 8 + q];
    }
    if (RELU) {
#pragma unroll
      for (int q = 0; q < 8; ++q) t[q] = fmaxf(t[q], 0.f);
    }
    if (POST) {
#pragma unroll
      for (int q = 0; q < 8; ++q) t[q] *= dv;
    }
    if (OUTF16) {
      half8v o;
#pragma unroll
      for (int q = 0; q < 8; ++q) o[q] = (_Float16)t[q];
      *(half8v*)&((_Float16*)outv)[rbase] = o;
    } else {
      float* op = &((float*)outv)[rbase];
      *(float4*)op = make_float4(t[0], t[1], t[2], t[3]);
      *(float4*)(op + 4) = make_float4(t[4], t[5], t[6], t[7]);
    }
  }
}

// C[N,M] = A[N,K] @ W[K,M] (+bias) (+relu) (*dinv[row]). 64x64 tile, 4x4/thr.
// OUTF16: store half4 (8B) instead of float4.
template <int BIAS, int RELU, int SCALE, int OUTF16>
__global__ __launch_bounds__(256) void k_gemm(const float* __restrict__ A,
                                              const float* __restrict__ W,
                                              const float* __restrict__ bias,
                                              const float* __restrict__ dinv,
                                              void* __restrict__ Cv,
                                              int N, int K, int M) {
  __shared__ float As[64][68];  // [k][row]
  __shared__ float Bs[64][68];  // [k][col]
  const int tid = threadIdx.x;
  const int tx = tid & 15;
  const int ty = tid >> 4;
  const int row0 = blockIdx.x * 64;
  const int col0 = blockIdx.y * 64;

  float acc[4][4] = {};

  for (int kt = 0; kt < K; kt += 64) {
#pragma unroll
    for (int i = 0; i < 4; ++i) {
      int fid = tid + i * 256;
      int r = fid >> 4;
      int c4 = (fid & 15) << 2;
      float4 v = make_float4(0.f, 0.f, 0.f, 0.f);
      int gr = row0 + r;
      if (gr < N) v = *(const float4*)&A[(size_t)gr * K + kt + c4];
      As[c4 + 0][r] = v.x;
      As[c4 + 1][r] = v.y;
      As[c4 + 2][r] = v.z;
      As[c4 + 3][r] = v.w;
      float4 w = *(const float4*)&W[(size_t)(kt + r) * M + col0 + c4];
      *(float4*)&Bs[r][c4] = w;
    }
    __syncthreads();

#pragma unroll 8
    for (int k = 0; k < 64; ++k) {
      float4 a4 = *(const float4*)&As[k][ty << 2];
      float4 b4 = *(const float4*)&Bs[k][tx << 2];
      float ar[4] = {a4.x, a4.y, a4.z, a4.w};
      float br[4] = {b4.x, b4.y, b4.z, b4.w};
#pragma unroll
      for (int i = 0; i < 4; ++i)
#pragma unroll
        for (int j = 0; j < 4; ++j) acc[i][j] += ar[i] * br[j];
    }
    __syncthreads();
  }

  float4 bv = make_float4(0.f, 0.f, 0.f, 0.f);
  if (BIAS) bv = *(const float4*)&bias[col0 + (tx << 2)];
#pragma unroll
  for (int i = 0; i < 4; ++i) {
    int gr = row0 + (ty << 2) + i;
    if (gr >= N) continue;
    float dv = SCALE ? dinv[gr] : 1.0f;
    float o[4];
#pragma unroll
    for (int j = 0; j < 4; ++j) {
      float v = acc[i][j] + (&bv.x)[j];
      if (RELU) v = fmaxf(v, 0.f);
      if (SCALE) v *= dv;
      o[j] = v;
    }
    size_t cidx = (size_t)gr * M + col0 + (tx << 2);
    if (OUTF16) {
      half4v h;
#pragma unroll
      for (int j = 0; j < 4; ++j) h[j] = (_Float16)o[j];
      *(half4v*)&((_Float16*)Cv)[cidx] = h;
    } else {
      *(float4*)&((float*)Cv)[cidx] = make_float4(o[0], o[1], o[2], o[3]);
    }
  }
}

extern "C" void kernel_launch(void* const* d_in, const int* in_sizes, int n_in,
                              void* d_out, int out_size, void* d_ws, size_t ws_size,
                              hipStream_t stream) {
  const float* x  = (const float*)d_in[0];
  const int*   ei = (const int*)d_in[1];
  const float* W1 = (const float*)d_in[2];
  const float* b1 = (const float*)d_in[3];
  const float* W2 = (const float*)d_in[4];
  const float* b2 = (const float*)d_in[5];
  const float* W3 = (const float*)d_in[6];
  const float* b3 = (const float*)d_in[7];
  const float* W4 = (const float*)d_in[8];
  const float* b4 = (const float*)d_in[9];

  const int N = in_sizes[0] / 256;  // 50000
  const int E = in_sizes[1] / 2;    // 1600000
  const int* src = ei;
  const int* dst = ei + E;
  const int nb = cdiv(N, 64);       // 782 buckets

  const int NP = 50176;  // padded N
  int*   bh     = (int*)d_ws;                      // NBMAX
  int*   boff   = bh + NBMAX;                      // NBMAX
  int*   bcur   = boff + NBMAX;                    // NBMAX
  int*   counts = bcur + NBMAX;                    // NP
  int*   offs   = counts + NP;                     // NP
  float* dinv   = (float*)(offs + NP);             // NP
  unsigned short* esrc = (unsigned short*)(dinv + NP);  // E u16
  _Float16* A16 = (_Float16*)(((uintptr_t)(esrc + E) + 255) & ~(uintptr_t)255);
  _Float16* B16 = A16 + (size_t)N * 128;           // N*128 halves each
  float* B32 = (float*)(((uintptr_t)(B16 + (size_t)N * 128) + 255) & ~(uintptr_t)255);
  unsigned* tmp = (unsigned*)B32;  // E u32 overlaid on B32 (dead before pull1)
  float* out = (float*)d_out;

  dim3 blk(256);

  // --- CSR build (2-level counting sort) + normalization ---
  (void)hipMemsetAsync(bh, 0, NBMAX * sizeof(int), stream);
  {
    int nblk = 256;
    int perBlock = cdiv(E, nblk);
    k_bhist<<<nblk, blk, 0, stream>>>(dst, bh, E, nb, perBlock);
  }
  k_bscan<<<1, blk, 0, stream>>>(bh, boff, bcur, nb);
  k_bscatter<<<cdiv(E, SCHUNK), blk, 0, stream>>>(src, dst, bcur, tmp, E, nb);
  k_bsort<<<nb, blk, 0, stream>>>(tmp, boff, esrc, offs, counts, dinv, N);

  dim3 gpull(cdiv(N, 4));

  // L1: t1' = dinv o (x @ W1) -> A16 ; h1 = relu(dinv*acc + b1) -> B32
  {
    dim3 g(cdiv(N, 64), 128 / 64);
    k_gemm<0, 0, 1, 1><<<g, blk, 0, stream>>>(x, W1, nullptr, dinv, A16, N, 256, 128);
    k_pull16<128, 1, 1, 0, 0><<<gpull, blk, 0, stream>>>(A16, esrc, offs, counts, dinv, b1, B32, N);
  }
  // L2: t2' = dinv o (h1 @ W2) -> A16 ; z' = dinv*relu(dinv*acc + b2) -> B16
  {
    dim3 g(cdiv(N, 64), 64 / 64);
    k_gemm<0, 0, 1, 1><<<g, blk, 0, stream>>>(B32, W2, nullptr, dinv, A16, N, 128, 64);
    k_pull16<64, 1, 1, 1, 1><<<gpull, blk, 0, stream>>>(A16, esrc, offs, counts, dinv, b2, B16, N);
  }
  // L3: p3 = dinv*acc(z') -> B32 ; h3' = dinv o relu(p3 @ W3 + b3) -> B16
  {
    k_pull16<64, 0, 0, 0, 0><<<gpull, blk, 0, stream>>>(B16, esrc, offs, counts, dinv, nullptr, B32, N);
    dim3 g(cdiv(N, 64), 128 / 64);
    k_gemm<1, 1, 1, 1><<<g, blk, 0, stream>>>(B32, W3, b3, dinv, B16, N, 64, 128);
  }
  // L4: p4 = dinv*acc(h3') -> B32 ; out = p4 @ W4 + b4
  {
    k_pull16<128, 0, 0, 0, 0><<<gpull, blk, 0, stream>>>(B16, esrc, offs, counts, dinv, nullptr, B32, N);
    dim3 g(cdiv(N, 64), 256 / 64);
    k_gemm<1, 0, 0, 0><<<g, blk, 0, stream>>>(B32, W4, b4, nullptr, out, N, 128, 256);
  }
}

// Round 10
// 352.501 us; speedup vs baseline: 2.0805x; 1.0617x over previous
//
#include <hip/hip_runtime.h>
#include <cstdint>
#include <cstddef>

// ---------------------------------------------------------------------------
// 4-layer GCN autoencoder, pull-based propagation + MFMA fp16 GEMMs.
// CSR built per launch with a 2-level counting sort (block-aggregated coarse
// scatter -> per-bucket LDS counting sort, u16 esrc).
// Propagation: out[d] = dinv[d]*sum_{s in N(d)u{d}} (dinv[s]*h[s]) (+b, relu);
// rows pre-scaled by dinv in the producer epilogue. All gathered/GEMM-input
// intermediates are fp16 (gather is L2-miss-byte-bound); accum fp32.
// GEMM: mfma_f32_16x16x32_f16, LDS-free. A-frag: 16B half8 from row-major A
// (row=l&15, k=(l>>4)*8+i; fp32 A converted in-register). B-frag: 16B half8
// from pre-transposed Wt[m][k]. A/B use the same lane->k map (permutation-
// safe); C/D map col=lane&15, row=(lane>>4)*4+reg (HW-verified).
// ---------------------------------------------------------------------------

static inline int cdiv(int a, int b) { return (a + b - 1) / b; }

typedef _Float16 half8v __attribute__((ext_vector_type(8)));
typedef float f32x4 __attribute__((ext_vector_type(4)));

#define NBMAX 784   // >= cdiv(50000,64)=782 buckets
#define SCHUNK 8192 // edges per scatter block

// coarse histogram over dst>>6 with LDS aggregation
__global__ __launch_bounds__(256) void k_bhist(const int* __restrict__ dst,
                                               int* __restrict__ bh,
                                               int E, int nb, int perBlock) {
  __shared__ int h[NBMAX];
  for (int i = threadIdx.x; i < nb; i += 256) h[i] = 0;
  __syncthreads();
  int beg = blockIdx.x * perBlock;
  int end = min(beg + perBlock, E);
  for (int e = beg + threadIdx.x; e < end; e += 256)
    atomicAdd(&h[dst[e] >> 6], 1);
  __syncthreads();
  for (int i = threadIdx.x; i < nb; i += 256)
    if (h[i]) atomicAdd(&bh[i], h[i]);
}

// single-block exclusive scan of nb (<=1024) bucket sums -> boff, bcur
__global__ __launch_bounds__(256) void k_bscan(const int* __restrict__ bh,
                                               int* __restrict__ boff,
                                               int* __restrict__ bcur, int nb) {
  __shared__ int tsum[256];
  int t = threadIdx.x;
  int v[4];
  int s = 0;
#pragma unroll
  for (int i = 0; i < 4; ++i) {
    int idx = t * 4 + i;
    v[i] = (idx < nb) ? bh[idx] : 0;
    s += v[i];
  }
  tsum[t] = s;
  __syncthreads();
  int x = s;
  for (int d = 1; d < 256; d <<= 1) {
    int add = (t >= d) ? tsum[t - d] : 0;
    __syncthreads();
    x += add;
    tsum[t] = x;
    __syncthreads();
  }
  int base = x - s;  // exclusive prefix
#pragma unroll
  for (int i = 0; i < 4; ++i) {
    int idx = t * 4 + i;
    if (idx < nb) { boff[idx] = base; bcur[idx] = base; }
    base += v[i];
  }
  if (t == 255) boff[nb] = base;  // == E
}

// block-aggregated coarse scatter: one global atomic per (block,bucket)
__global__ __launch_bounds__(256) void k_bscatter(const int* __restrict__ src,
                                                  const int* __restrict__ dst,
                                                  int* __restrict__ bcur,
                                                  unsigned* __restrict__ tmp,
                                                  int E, int nb) {
  __shared__ int hist[NBMAX];
  __shared__ int base[NBMAX];
  int beg = blockIdx.x * SCHUNK;
  int end = min(beg + SCHUNK, E);
  for (int i = threadIdx.x; i < nb; i += 256) hist[i] = 0;
  __syncthreads();
  for (int e = beg + threadIdx.x; e < end; e += 256)
    atomicAdd(&hist[dst[e] >> 6], 1);
  __syncthreads();
  for (int b = threadIdx.x; b < nb; b += 256) {
    int c = hist[b];
    base[b] = c ? atomicAdd(&bcur[b], c) : 0;
    hist[b] = 0;  // reuse as local cursor
  }
  __syncthreads();
  for (int e = beg + threadIdx.x; e < end; e += 256) {
    int d = dst[e];
    int b = d >> 6;
    int lp = atomicAdd(&hist[b], 1);
    tmp[base[b] + lp] = ((unsigned)(d & 63) << 16) | (unsigned)src[e];
  }
}

// per-bucket counting sort (64 bins in LDS); emits u16 esrc, counts/offs/dinv
__global__ __launch_bounds__(256) void k_bsort(const unsigned* __restrict__ tmp,
                                               const int* __restrict__ boff,
                                               unsigned short* __restrict__ esrc,
                                               int* __restrict__ offs,
                                               int* __restrict__ counts,
                                               float* __restrict__ dinv,
                                               int N) {
  __shared__ int hist[64], cur[64];
  int b = blockIdx.x;
  int t = threadIdx.x;
  if (t < 64) hist[t] = 0;
  __syncthreads();
  int beg = boff[b], end = boff[b + 1];
  int cnt = end - beg;
  for (int i = t; i < cnt; i += 256) atomicAdd(&hist[tmp[beg + i] >> 16], 1);
  __syncthreads();
  if (t < 64) {
    int v = hist[t];
    int x = v;
#pragma unroll
    for (int d = 1; d < 64; d <<= 1) {
      int up = __shfl_up(x, d, 64);
      if (t >= d) x += up;
    }
    int ex = x - v;
    cur[t] = ex;
    int node = b * 64 + t;
    if (node < N) {
      counts[node] = v;
      offs[node] = beg + ex;
      dinv[node] = rsqrtf((float)(v + 1));
    }
  }
  __syncthreads();
  for (int i = t; i < cnt; i += 256) {
    unsigned v = tmp[beg + i];
    int pos = atomicAdd(&cur[v >> 16], 1);
    esrc[beg + pos] = (unsigned short)(v & 0xFFFFu);
  }
}

// transpose+cast all weight matrices to fp16: Wt[m][k] = (fp16)W[k][m]
__global__ __launch_bounds__(256) void k_prepw(const float* __restrict__ W1,
                                               const float* __restrict__ W2,
                                               const float* __restrict__ W3,
                                               const float* __restrict__ W4,
                                               _Float16* __restrict__ W1t,
                                               _Float16* __restrict__ W2t,
                                               _Float16* __restrict__ W3t,
                                               _Float16* __restrict__ W4t) {
  int t = blockIdx.x * 256 + threadIdx.x;
  if (t < 32768) {                      // W1 [256][128] -> W1t [128][256]
    int m = t >> 8, k = t & 255;
    W1t[t] = (_Float16)W1[k * 128 + m];
  } else if (t < 40960) {               // W2 [128][64] -> W2t [64][128]
    int u = t - 32768;
    int m = u >> 7, k = u & 127;
    W2t[u] = (_Float16)W2[k * 64 + m];
  } else if (t < 49152) {               // W3 [64][128] -> W3t [128][64]
    int u = t - 40960;
    int m = u >> 6, k = u & 63;
    W3t[u] = (_Float16)W3[k * 128 + m];
  } else if (t < 81920) {               // W4 [128][256] -> W4t [256][128]
    int u = t - 49152;
    int m = u >> 7, k = u & 127;
    W4t[u] = (_Float16)W4[k * 256 + m];
  }
}

// fp16-gather pull. W = halves per row (128 or 64). One wave per node.
// LPR = W/8 lanes cover a row with 16B half8 loads; GRP = 64/LPR edges per
// wave load instruction (4 at w128, 8 at w64), 2x unrolled.
// Epilogue (group 0): t = dinv*acc (+bias) (relu) (*dinv); fp16 output.
template <int W, int BIAS, int RELU, int POST>
__global__ __launch_bounds__(256) void k_pull16(const _Float16* __restrict__ h,
                                                const unsigned short* __restrict__ esrc,
                                                const int* __restrict__ offs,
                                                const int* __restrict__ counts,
                                                const float* __restrict__ dinv,
                                                const float* __restrict__ bias,
                                                _Float16* __restrict__ out, int n) {
  const int LPR = W / 8;    // lanes per row: 16 (w128) / 8 (w64)
  const int GRP = 64 / LPR; // edge groups:    4        / 8
  int node = blockIdx.x * 4 + (threadIdx.x >> 6);
  if (node >= n) return;
  int lane = threadIdx.x & 63;
  int g  = lane / LPR;
  int fl = lane % LPR;
  size_t rbase = (size_t)node * W + fl * 8;

  float acc[8] = {};
  if (g == 0) {
    half8v sv = *(const half8v*)&h[rbase];  // self loop
#pragma unroll
    for (int q = 0; q < 8; ++q) acc[q] = (float)sv[q];
  }

  int beg = offs[node];
  int cnt = counts[node];
  int j = g;
  for (; j + GRP < cnt; j += 2 * GRP) {
    int s0 = esrc[beg + j];
    int s1 = esrc[beg + j + GRP];
    half8v v0 = *(const half8v*)&h[(size_t)s0 * W + fl * 8];
    half8v v1 = *(const half8v*)&h[(size_t)s1 * W + fl * 8];
#pragma unroll
    for (int q = 0; q < 8; ++q) acc[q] += (float)v0[q] + (float)v1[q];
  }
  if (j < cnt) {
    int s = esrc[beg + j];
    half8v v = *(const half8v*)&h[(size_t)s * W + fl * 8];
#pragma unroll
    for (int q = 0; q < 8; ++q) acc[q] += (float)v[q];
  }

  // reduce partial sums across edge-groups (same fl, different g)
#pragma unroll
  for (int d = LPR; d < 64; d <<= 1) {
#pragma unroll
    for (int q = 0; q < 8; ++q) acc[q] += __shfl_xor(acc[q], d, 64);
  }

  if (g == 0) {
    float dv = dinv[node];
    float t[8];
#pragma unroll
    for (int q = 0; q < 8; ++q) t[q] = dv * acc[q];
    if (BIAS) {
#pragma unroll
      for (int q = 0; q < 8; ++q) t[q] += bias[fl * 8 + q];
    }
    if (RELU) {
#pragma unroll
      for (int q = 0; q < 8; ++q) t[q] = fmaxf(t[q], 0.f);
    }
    if (POST) {
#pragma unroll
      for (int q = 0; q < 8; ++q) t[q] *= dv;
    }
    half8v o;
#pragma unroll
    for (int q = 0; q < 8; ++q) o[q] = (_Float16)t[q];
    *(half8v*)&out[rbase] = o;
  }
}

// MFMA fp16 GEMM: C[N,M] = A[N,K] @ W[K,M] (+bias) (+relu) (*dinv[row]).
// Block = 4 waves, each wave 16 rows x M cols; no LDS.
// AF32: A is fp32, converted to fp16 in-register at load.
// OUTF16: store fp16, else fp32.
template <int M, int K, int BIAS, int RELU, int SCALE, int AF32, int OUTF16>
__global__ __launch_bounds__(256) void k_gemm_mfma(const void* __restrict__ Av,
                                                   const _Float16* __restrict__ Wt,
                                                   const float* __restrict__ bias,
                                                   const float* __restrict__ dinv,
                                                   void* __restrict__ Cv, int N) {
  const int NT = M / 16;               // col tiles
  const int w  = threadIdx.x >> 6;     // wave 0..3
  const int l  = threadIdx.x & 63;
  const int lr = l & 15;               // A-row / B-col / C-col within tile
  const int lk = l >> 4;               // k-octet selector / C-row quad
  const int r0 = blockIdx.x * 64 + w * 16;
  int arow = r0 + lr;
  if (arow >= N) arow = N - 1;         // clamp: OOB rows never stored

  f32x4 acc[NT] = {};

  for (int k0 = 0; k0 < K; k0 += 32) {
    half8v a;
    if (AF32) {
      const float* ap = &((const float*)Av)[(size_t)arow * K + k0 + lk * 8];
      float4 f0 = *(const float4*)ap;
      float4 f1 = *(const float4*)(ap + 4);
      a[0] = (_Float16)f0.x; a[1] = (_Float16)f0.y;
      a[2] = (_Float16)f0.z; a[3] = (_Float16)f0.w;
      a[4] = (_Float16)f1.x; a[5] = (_Float16)f1.y;
      a[6] = (_Float16)f1.z; a[7] = (_Float16)f1.w;
    } else {
      a = *(const half8v*)&((const _Float16*)Av)[(size_t)arow * K + k0 + lk * 8];
    }
#pragma unroll
    for (int ct = 0; ct < NT; ++ct) {
      half8v b = *(const half8v*)&Wt[(size_t)(ct * 16 + lr) * K + k0 + lk * 8];
      acc[ct] = __builtin_amdgcn_mfma_f32_16x16x32_f16(a, b, acc[ct], 0, 0, 0);
    }
  }

  // epilogue: C row = r0 + lk*4 + r, col = ct*16 + lr
  float dvv[4];
  int okr[4];
#pragma unroll
  for (int r = 0; r < 4; ++r) {
    int ro = r0 + lk * 4 + r;
    okr[r] = (ro < N);
    dvv[r] = (SCALE && okr[r]) ? dinv[ro] : 1.0f;
  }
#pragma unroll
  for (int ct = 0; ct < NT; ++ct) {
    int col = ct * 16 + lr;
    float bs = BIAS ? bias[col] : 0.f;
#pragma unroll
    for (int r = 0; r < 4; ++r) {
      if (!okr[r]) continue;
      int ro = r0 + lk * 4 + r;
      float v = acc[ct][r] + bs;
      if (RELU) v = fmaxf(v, 0.f);
      if (SCALE) v *= dvv[r];
      if (OUTF16) ((_Float16*)Cv)[(size_t)ro * M + col] = (_Float16)v;
      else        ((float*)Cv)[(size_t)ro * M + col] = v;
    }
  }
}

extern "C" void kernel_launch(void* const* d_in, const int* in_sizes, int n_in,
                              void* d_out, int out_size, void* d_ws, size_t ws_size,
                              hipStream_t stream) {
  const float* x  = (const float*)d_in[0];
  const int*   ei = (const int*)d_in[1];
  const float* W1 = (const float*)d_in[2];
  const float* b1 = (const float*)d_in[3];
  const float* W2 = (const float*)d_in[4];
  const float* b2 = (const float*)d_in[5];
  const float* W3 = (const float*)d_in[6];
  const float* b3 = (const float*)d_in[7];
  const float* W4 = (const float*)d_in[8];
  const float* b4 = (const float*)d_in[9];

  const int N = in_sizes[0] / 256;  // 50000
  const int E = in_sizes[1] / 2;    // 1600000
  const int* src = ei;
  const int* dst = ei + E;
  const int nb = cdiv(N, 64);       // 782 buckets

  const int NP = 50176;  // padded N
  int*   bh     = (int*)d_ws;                      // NBMAX
  int*   boff   = bh + NBMAX;                      // NBMAX
  int*   bcur   = boff + NBMAX;                    // NBMAX
  int*   counts = bcur + NBMAX;                    // NP
  int*   offs   = counts + NP;                     // NP
  float* dinv   = (float*)(offs + NP);             // NP
  unsigned short* esrc = (unsigned short*)(dinv + NP);  // E u16
  _Float16* W1t = (_Float16*)(esrc + E);           // 32768 halves
  _Float16* W2t = W1t + 32768;                     // 8192
  _Float16* W3t = W2t + 8192;                      // 8192
  _Float16* W4t = W3t + 8192;                      // 32768
  _Float16* bufA = (_Float16*)(((uintptr_t)(W4t + 32768) + 255) & ~(uintptr_t)255);
  _Float16* bufB = bufA + (size_t)N * 128;         // N*128 halves each
  _Float16* bufC = bufB + (size_t)N * 128;         // N*64 halves
  _Float16* bufD = bufC + (size_t)N * 64;          // N*64 halves
  unsigned* tmp = (unsigned*)bufA;  // E u32 overlay (dead before GEMM1 writes)
  float* out = (float*)d_out;

  dim3 blk(256);

  // --- weight transpose/cast + CSR build ---
  k_prepw<<<320, blk, 0, stream>>>(W1, W2, W3, W4, W1t, W2t, W3t, W4t);
  (void)hipMemsetAsync(bh, 0, NBMAX * sizeof(int), stream);
  {
    int nblk = 256;
    int perBlock = cdiv(E, nblk);
    k_bhist<<<nblk, blk, 0, stream>>>(dst, bh, E, nb, perBlock);
  }
  k_bscan<<<1, blk, 0, stream>>>(bh, boff, bcur, nb);
  k_bscatter<<<cdiv(E, SCHUNK), blk, 0, stream>>>(src, dst, bcur, tmp, E, nb);
  k_bsort<<<nb, blk, 0, stream>>>(tmp, boff, esrc, offs, counts, dinv, N);

  dim3 gpull(cdiv(N, 4));
  dim3 ggemm(cdiv(N, 64));

  // L1: t1' = dinv o (x @ W1) -> bufA ; h1 = relu(dinv*acc + b1) -> bufB
  k_gemm_mfma<128, 256, 0, 0, 1, 1, 1><<<ggemm, blk, 0, stream>>>(x, W1t, nullptr, dinv, bufA, N);
  k_pull16<128, 1, 1, 0><<<gpull, blk, 0, stream>>>(bufA, esrc, offs, counts, dinv, b1, bufB, N);
  // L2: t2' = dinv o (h1 @ W2) -> bufC ; z' = dinv*relu(dinv*acc + b2) -> bufD
  k_gemm_mfma<64, 128, 0, 0, 1, 0, 1><<<ggemm, blk, 0, stream>>>(bufB, W2t, nullptr, dinv, bufC, N);
  k_pull16<64, 1, 1, 1><<<gpull, blk, 0, stream>>>(bufC, esrc, offs, counts, dinv, b2, bufD, N);
  // L3: p3 = dinv*acc(z') -> bufC ; h3' = dinv o relu(p3 @ W3 + b3) -> bufA
  k_pull16<64, 0, 0, 0><<<gpull, blk, 0, stream>>>(bufD, esrc, offs, counts, dinv, nullptr, bufC, N);
  k_gemm_mfma<128, 64, 1, 1, 1, 0, 1><<<ggemm, blk, 0, stream>>>(bufC, W3t, b3, dinv, bufA, N);
  // L4: p4 = dinv*acc(h3') -> bufB ; out = p4 @ W4 + b4 (fp32)
  k_pull16<128, 0, 0, 0><<<gpull, blk, 0, stream>>>(bufA, esrc, offs, counts, dinv, nullptr, bufB, N);
  k_gemm_mfma<256, 128, 1, 0, 0, 0, 0><<<ggemm, blk, 0, stream>>>(bufB, W4t, b4, nullptr, out, N);
}

// Round 11
// 335.453 us; speedup vs baseline: 2.1862x; 1.0508x over previous
//
#include <hip/hip_runtime.h>
#include <cstdint>
#include <cstddef>

// ---------------------------------------------------------------------------
// 4-layer GCN autoencoder, pull-based propagation + MFMA fp16 GEMMs.
// CSR built per launch with a 2-level counting sort (block-aggregated coarse
// scatter -> per-bucket LDS counting sort, u16 esrc).
// Propagation: out[d] = dinv[d]*sum_{s in N(d)u{d}} (dinv[s]*h[s]) (+b, relu);
// rows pre-scaled by dinv in the producer epilogue. All gathered/GEMM-input
// intermediates are fp16 (gather is L2-miss-byte-bound); accum fp32.
// GEMM (R10): column-split grid (cdiv(N,64) x M/64); each wave = 16 rows x
// 64 cols (NT=4) -> 4x blocks, short dep chains, occupancy-bound fix.
// A-frag: 16B half8 row-major (row=l&15, k-octet=l>>4); B-frag from
// pre-transposed Wt[m][k]; C/D map col=lane&15, row=(lane>>4)*4+reg.
// ---------------------------------------------------------------------------

static inline int cdiv(int a, int b) { return (a + b - 1) / b; }

typedef _Float16 half8v __attribute__((ext_vector_type(8)));
typedef float f32x4 __attribute__((ext_vector_type(4)));

#define NBMAX 784   // >= cdiv(50000,64)=782 buckets
#define SCHUNK 8192 // edges per scatter block

// coarse histogram over dst>>6 with LDS aggregation
__global__ __launch_bounds__(256) void k_bhist(const int* __restrict__ dst,
                                               int* __restrict__ bh,
                                               int E, int nb, int perBlock) {
  __shared__ int h[NBMAX];
  for (int i = threadIdx.x; i < nb; i += 256) h[i] = 0;
  __syncthreads();
  int beg = blockIdx.x * perBlock;
  int end = min(beg + perBlock, E);
  for (int e = beg + threadIdx.x; e < end; e += 256)
    atomicAdd(&h[dst[e] >> 6], 1);
  __syncthreads();
  for (int i = threadIdx.x; i < nb; i += 256)
    if (h[i]) atomicAdd(&bh[i], h[i]);
}

// single-block exclusive scan of nb (<=1024) bucket sums -> boff, bcur
__global__ __launch_bounds__(256) void k_bscan(const int* __restrict__ bh,
                                               int* __restrict__ boff,
                                               int* __restrict__ bcur, int nb) {
  __shared__ int tsum[256];
  int t = threadIdx.x;
  int v[4];
  int s = 0;
#pragma unroll
  for (int i = 0; i < 4; ++i) {
    int idx = t * 4 + i;
    v[i] = (idx < nb) ? bh[idx] : 0;
    s += v[i];
  }
  tsum[t] = s;
  __syncthreads();
  int x = s;
  for (int d = 1; d < 256; d <<= 1) {
    int add = (t >= d) ? tsum[t - d] : 0;
    __syncthreads();
    x += add;
    tsum[t] = x;
    __syncthreads();
  }
  int base = x - s;  // exclusive prefix
#pragma unroll
  for (int i = 0; i < 4; ++i) {
    int idx = t * 4 + i;
    if (idx < nb) { boff[idx] = base; bcur[idx] = base; }
    base += v[i];
  }
  if (t == 255) boff[nb] = base;  // == E
}

// block-aggregated coarse scatter: one global atomic per (block,bucket)
__global__ __launch_bounds__(256) void k_bscatter(const int* __restrict__ src,
                                                  const int* __restrict__ dst,
                                                  int* __restrict__ bcur,
                                                  unsigned* __restrict__ tmp,
                                                  int E, int nb) {
  __shared__ int hist[NBMAX];
  __shared__ int base[NBMAX];
  int beg = blockIdx.x * SCHUNK;
  int end = min(beg + SCHUNK, E);
  for (int i = threadIdx.x; i < nb; i += 256) hist[i] = 0;
  __syncthreads();
  for (int e = beg + threadIdx.x; e < end; e += 256)
    atomicAdd(&hist[dst[e] >> 6], 1);
  __syncthreads();
  for (int b = threadIdx.x; b < nb; b += 256) {
    int c = hist[b];
    base[b] = c ? atomicAdd(&bcur[b], c) : 0;
    hist[b] = 0;  // reuse as local cursor
  }
  __syncthreads();
  for (int e = beg + threadIdx.x; e < end; e += 256) {
    int d = dst[e];
    int b = d >> 6;
    int lp = atomicAdd(&hist[b], 1);
    tmp[base[b] + lp] = ((unsigned)(d & 63) << 16) | (unsigned)src[e];
  }
}

// per-bucket counting sort (64 bins in LDS); emits u16 esrc, counts/offs/dinv
__global__ __launch_bounds__(256) void k_bsort(const unsigned* __restrict__ tmp,
                                               const int* __restrict__ boff,
                                               unsigned short* __restrict__ esrc,
                                               int* __restrict__ offs,
                                               int* __restrict__ counts,
                                               float* __restrict__ dinv,
                                               int N) {
  __shared__ int hist[64], cur[64];
  int b = blockIdx.x;
  int t = threadIdx.x;
  if (t < 64) hist[t] = 0;
  __syncthreads();
  int beg = boff[b], end = boff[b + 1];
  int cnt = end - beg;
  for (int i = t; i < cnt; i += 256) atomicAdd(&hist[tmp[beg + i] >> 16], 1);
  __syncthreads();
  if (t < 64) {
    int v = hist[t];
    int x = v;
#pragma unroll
    for (int d = 1; d < 64; d <<= 1) {
      int up = __shfl_up(x, d, 64);
      if (t >= d) x += up;
    }
    int ex = x - v;
    cur[t] = ex;
    int node = b * 64 + t;
    if (node < N) {
      counts[node] = v;
      offs[node] = beg + ex;
      dinv[node] = rsqrtf((float)(v + 1));
    }
  }
  __syncthreads();
  for (int i = t; i < cnt; i += 256) {
    unsigned v = tmp[beg + i];
    int pos = atomicAdd(&cur[v >> 16], 1);
    esrc[beg + pos] = (unsigned short)(v & 0xFFFFu);
  }
}

// transpose+cast all weight matrices to fp16: Wt[m][k] = (fp16)W[k][m]
__global__ __launch_bounds__(256) void k_prepw(const float* __restrict__ W1,
                                               const float* __restrict__ W2,
                                               const float* __restrict__ W3,
                                               const float* __restrict__ W4,
                                               _Float16* __restrict__ W1t,
                                               _Float16* __restrict__ W2t,
                                               _Float16* __restrict__ W3t,
                                               _Float16* __restrict__ W4t) {
  int t = blockIdx.x * 256 + threadIdx.x;
  if (t < 32768) {                      // W1 [256][128] -> W1t [128][256]
    int m = t >> 8, k = t & 255;
    W1t[t] = (_Float16)W1[k * 128 + m];
  } else if (t < 40960) {               // W2 [128][64] -> W2t [64][128]
    int u = t - 32768;
    int m = u >> 7, k = u & 127;
    W2t[u] = (_Float16)W2[k * 64 + m];
  } else if (t < 49152) {               // W3 [64][128] -> W3t [128][64]
    int u = t - 40960;
    int m = u >> 6, k = u & 63;
    W3t[u] = (_Float16)W3[k * 128 + m];
  } else if (t < 81920) {               // W4 [128][256] -> W4t [256][128]
    int u = t - 49152;
    int m = u >> 7, k = u & 127;
    W4t[u] = (_Float16)W4[k * 256 + m];
  }
}

// fp16-gather pull. W = halves per row (128 or 64). One wave per node.
// LPR = W/8 lanes cover a row with 16B half8 loads; GRP = 64/LPR edges per
// wave load instruction (4 at w128, 8 at w64), 2x unrolled.
// Epilogue (group 0): t = dinv*acc (+bias) (relu) (*dinv); fp16 output.
template <int W, int BIAS, int RELU, int POST>
__global__ __launch_bounds__(256) void k_pull16(const _Float16* __restrict__ h,
                                                const unsigned short* __restrict__ esrc,
                                                const int* __restrict__ offs,
                                                const int* __restrict__ counts,
                                                const float* __restrict__ dinv,
                                                const float* __restrict__ bias,
                                                _Float16* __restrict__ out, int n) {
  const int LPR = W / 8;    // lanes per row: 16 (w128) / 8 (w64)
  const int GRP = 64 / LPR; // edge groups:    4        / 8
  int node = blockIdx.x * 4 + (threadIdx.x >> 6);
  if (node >= n) return;
  int lane = threadIdx.x & 63;
  int g  = lane / LPR;
  int fl = lane % LPR;
  size_t rbase = (size_t)node * W + fl * 8;

  float acc[8] = {};
  if (g == 0) {
    half8v sv = *(const half8v*)&h[rbase];  // self loop
#pragma unroll
    for (int q = 0; q < 8; ++q) acc[q] = (float)sv[q];
  }

  int beg = offs[node];
  int cnt = counts[node];
  int j = g;
  for (; j + GRP < cnt; j += 2 * GRP) {
    int s0 = esrc[beg + j];
    int s1 = esrc[beg + j + GRP];
    half8v v0 = *(const half8v*)&h[(size_t)s0 * W + fl * 8];
    half8v v1 = *(const half8v*)&h[(size_t)s1 * W + fl * 8];
#pragma unroll
    for (int q = 0; q < 8; ++q) acc[q] += (float)v0[q] + (float)v1[q];
  }
  if (j < cnt) {
    int s = esrc[beg + j];
    half8v v = *(const half8v*)&h[(size_t)s * W + fl * 8];
#pragma unroll
    for (int q = 0; q < 8; ++q) acc[q] += (float)v[q];
  }

  // reduce partial sums across edge-groups (same fl, different g)
#pragma unroll
  for (int d = LPR; d < 64; d <<= 1) {
#pragma unroll
    for (int q = 0; q < 8; ++q) acc[q] += __shfl_xor(acc[q], d, 64);
  }

  if (g == 0) {
    float dv = dinv[node];
    float t[8];
#pragma unroll
    for (int q = 0; q < 8; ++q) t[q] = dv * acc[q];
    if (BIAS) {
#pragma unroll
      for (int q = 0; q < 8; ++q) t[q] += bias[fl * 8 + q];
    }
    if (RELU) {
#pragma unroll
      for (int q = 0; q < 8; ++q) t[q] = fmaxf(t[q], 0.f);
    }
    if (POST) {
#pragma unroll
      for (int q = 0; q < 8; ++q) t[q] *= dv;
    }
    half8v o;
#pragma unroll
    for (int q = 0; q < 8; ++q) o[q] = (_Float16)t[q];
    *(half8v*)&out[rbase] = o;
  }
}

// MFMA fp16 GEMM, column-split: C[N,M] = A[N,K] @ W[K,M] (+bias)(+relu)(*dinv).
// Grid (cdiv(N,64), M/64); block = 4 waves; wave = 16 rows x 64 cols (NT=4).
// AF32: A is fp32, converted in-register. OUTF16: store fp16 else fp32.
template <int M, int K, int BIAS, int RELU, int SCALE, int AF32, int OUTF16>
__global__ __launch_bounds__(256) void k_gemm_mfma(const void* __restrict__ Av,
                                                   const _Float16* __restrict__ Wt,
                                                   const float* __restrict__ bias,
                                                   const float* __restrict__ dinv,
                                                   void* __restrict__ Cv, int N) {
  const int w  = threadIdx.x >> 6;     // wave 0..3
  const int l  = threadIdx.x & 63;
  const int lr = l & 15;               // A-row / B-col / C-col within tile
  const int lk = l >> 4;               // k-octet selector / C-row quad
  const int r0 = blockIdx.x * 64 + w * 16;
  const int col0 = blockIdx.y * 64;
  int arow = r0 + lr;
  if (arow >= N) arow = N - 1;         // clamp: OOB rows never stored

  f32x4 acc[4] = {};

  for (int k0 = 0; k0 < K; k0 += 32) {
    half8v a;
    if (AF32) {
      const float* ap = &((const float*)Av)[(size_t)arow * K + k0 + lk * 8];
      float4 f0 = *(const float4*)ap;
      float4 f1 = *(const float4*)(ap + 4);
      a[0] = (_Float16)f0.x; a[1] = (_Float16)f0.y;
      a[2] = (_Float16)f0.z; a[3] = (_Float16)f0.w;
      a[4] = (_Float16)f1.x; a[5] = (_Float16)f1.y;
      a[6] = (_Float16)f1.z; a[7] = (_Float16)f1.w;
    } else {
      a = *(const half8v*)&((const _Float16*)Av)[(size_t)arow * K + k0 + lk * 8];
    }
#pragma unroll
    for (int ct = 0; ct < 4; ++ct) {
      half8v b = *(const half8v*)&Wt[(size_t)(col0 + ct * 16 + lr) * K + k0 + lk * 8];
      acc[ct] = __builtin_amdgcn_mfma_f32_16x16x32_f16(a, b, acc[ct], 0, 0, 0);
    }
  }

  // epilogue: C row = r0 + lk*4 + r, col = col0 + ct*16 + lr
  float dvv[4];
  int okr[4];
#pragma unroll
  for (int r = 0; r < 4; ++r) {
    int ro = r0 + lk * 4 + r;
    okr[r] = (ro < N);
    dvv[r] = (SCALE && okr[r]) ? dinv[ro] : 1.0f;
  }
#pragma unroll
  for (int ct = 0; ct < 4; ++ct) {
    int col = col0 + ct * 16 + lr;
    float bs = BIAS ? bias[col] : 0.f;
#pragma unroll
    for (int r = 0; r < 4; ++r) {
      if (!okr[r]) continue;
      int ro = r0 + lk * 4 + r;
      float v = acc[ct][r] + bs;
      if (RELU) v = fmaxf(v, 0.f);
      if (SCALE) v *= dvv[r];
      if (OUTF16) ((_Float16*)Cv)[(size_t)ro * M + col] = (_Float16)v;
      else        ((float*)Cv)[(size_t)ro * M + col] = v;
    }
  }
}

extern "C" void kernel_launch(void* const* d_in, const int* in_sizes, int n_in,
                              void* d_out, int out_size, void* d_ws, size_t ws_size,
                              hipStream_t stream) {
  const float* x  = (const float*)d_in[0];
  const int*   ei = (const int*)d_in[1];
  const float* W1 = (const float*)d_in[2];
  const float* b1 = (const float*)d_in[3];
  const float* W2 = (const float*)d_in[4];
  const float* b2 = (const float*)d_in[5];
  const float* W3 = (const float*)d_in[6];
  const float* b3 = (const float*)d_in[7];
  const float* W4 = (const float*)d_in[8];
  const float* b4 = (const float*)d_in[9];

  const int N = in_sizes[0] / 256;  // 50000
  const int E = in_sizes[1] / 2;    // 1600000
  const int* src = ei;
  const int* dst = ei + E;
  const int nb = cdiv(N, 64);       // 782 buckets

  const int NP = 50176;  // padded N
  int*   bh     = (int*)d_ws;                      // NBMAX
  int*   boff   = bh + NBMAX;                      // NBMAX
  int*   bcur   = boff + NBMAX;                    // NBMAX
  int*   counts = bcur + NBMAX;                    // NP
  int*   offs   = counts + NP;                     // NP
  float* dinv   = (float*)(offs + NP);             // NP
  unsigned short* esrc = (unsigned short*)(dinv + NP);  // E u16
  _Float16* W1t = (_Float16*)(esrc + E);           // 32768 halves
  _Float16* W2t = W1t + 32768;                     // 8192
  _Float16* W3t = W2t + 8192;                      // 8192
  _Float16* W4t = W3t + 8192;                      // 32768
  _Float16* bufA = (_Float16*)(((uintptr_t)(W4t + 32768) + 255) & ~(uintptr_t)255);
  _Float16* bufB = bufA + (size_t)N * 128;         // N*128 halves each
  _Float16* bufC = bufB + (size_t)N * 128;         // N*64 halves
  _Float16* bufD = bufC + (size_t)N * 64;          // N*64 halves
  unsigned* tmp = (unsigned*)bufA;  // E u32 overlay (dead before GEMM1 writes)
  float* out = (float*)d_out;

  dim3 blk(256);

  // --- weight transpose/cast + CSR build ---
  k_prepw<<<320, blk, 0, stream>>>(W1, W2, W3, W4, W1t, W2t, W3t, W4t);
  (void)hipMemsetAsync(bh, 0, NBMAX * sizeof(int), stream);
  {
    int nblk = 256;
    int perBlock = cdiv(E, nblk);
    k_bhist<<<nblk, blk, 0, stream>>>(dst, bh, E, nb, perBlock);
  }
  k_bscan<<<1, blk, 0, stream>>>(bh, boff, bcur, nb);
  k_bscatter<<<cdiv(E, SCHUNK), blk, 0, stream>>>(src, dst, bcur, tmp, E, nb);
  k_bsort<<<nb, blk, 0, stream>>>(tmp, boff, esrc, offs, counts, dinv, N);

  dim3 gpull(cdiv(N, 4));
  const int gx = cdiv(N, 64);

  // L1: t1' = dinv o (x @ W1) -> bufA ; h1 = relu(dinv*acc + b1) -> bufB
  k_gemm_mfma<128, 256, 0, 0, 1, 1, 1><<<dim3(gx, 2), blk, 0, stream>>>(x, W1t, nullptr, dinv, bufA, N);
  k_pull16<128, 1, 1, 0><<<gpull, blk, 0, stream>>>(bufA, esrc, offs, counts, dinv, b1, bufB, N);
  // L2: t2' = dinv o (h1 @ W2) -> bufC ; z' = dinv*relu(dinv*acc + b2) -> bufD
  k_gemm_mfma<64, 128, 0, 0, 1, 0, 1><<<dim3(gx, 1), blk, 0, stream>>>(bufB, W2t, nullptr, dinv, bufC, N);
  k_pull16<64, 1, 1, 1><<<gpull, blk, 0, stream>>>(bufC, esrc, offs, counts, dinv, b2, bufD, N);
  // L3: p3 = dinv*acc(z') -> bufC ; h3' = dinv o relu(p3 @ W3 + b3) -> bufA
  k_pull16<64, 0, 0, 0><<<gpull, blk, 0, stream>>>(bufD, esrc, offs, counts, dinv, nullptr, bufC, N);
  k_gemm_mfma<128, 64, 1, 1, 1, 0, 1><<<dim3(gx, 2), blk, 0, stream>>>(bufC, W3t, b3, dinv, bufA, N);
  // L4: p4 = dinv*acc(h3') -> bufB ; out = p4 @ W4 + b4 (fp32)
  k_pull16<128, 0, 0, 0><<<gpull, blk, 0, stream>>>(bufA, esrc, offs, counts, dinv, nullptr, bufB, N);
  k_gemm_mfma<256, 128, 1, 0, 0, 0, 0><<<dim3(gx, 4), blk, 0, stream>>>(bufB, W4t, b4, nullptr, out, N);
}